// Round 1
// baseline (8270.257 us; speedup 1.0000x reference)
//
#include <hip/hip_runtime.h>
#include <math.h>
#include <float.h>

#define RB 256      // batch
#define RS 32       // seq len
#define RV 10000    // vocab
#define RDE 512     // emb dim
#define RDH 1024    // hidden dim
#define RDI 2048    // image dim
#define RBOS 1
#define REOS 2
#define RVT 64      // v-tile in logits kernel
#define RNVT 157    // ceil(RV / RVT)

// ---------------------------------------------------------------------------
// h0 = image @ W_b   [256,2048]@[2048,1024]
// grid (RDH/64, RB/32), 256 threads, tile 32b x 64j, K chunks of 32
// ---------------------------------------------------------------------------
__global__ __launch_bounds__(256) void k_h0(const float* __restrict__ image,
                                            const float* __restrict__ Wb,
                                            float* __restrict__ h) {
  __shared__ float a_s[32 * 36];
  __shared__ float w_s[32 * 68];
  const int t = threadIdx.x;
  const int j0 = blockIdx.x * 64;
  const int b0 = blockIdx.y * 32;
  const int tv = t & 15, tb = t >> 4;
  const int arow = t >> 3, ac = (t & 7) * 4;
  const int w0r = t >> 4, w0c = (t & 15) * 4;
  float acc[2][4] = {};
  float4 pa, pw0, pw1;

  pa = *(const float4*)&image[(size_t)(b0 + arow) * RDI + ac];
  pw0 = *(const float4*)&Wb[(size_t)(w0r) * RDH + j0 + w0c];
  pw1 = *(const float4*)&Wb[(size_t)(16 + w0r) * RDH + j0 + w0c];

  for (int kc = 0; kc < RDI; kc += 32) {
    __syncthreads();
    *(float4*)&a_s[arow * 36 + ac] = pa;
    *(float4*)&w_s[w0r * 68 + w0c] = pw0;
    *(float4*)&w_s[(16 + w0r) * 68 + w0c] = pw1;
    __syncthreads();
    if (kc + 32 < RDI) {
      const int kn = kc + 32;
      pa = *(const float4*)&image[(size_t)(b0 + arow) * RDI + kn + ac];
      pw0 = *(const float4*)&Wb[(size_t)(kn + w0r) * RDH + j0 + w0c];
      pw1 = *(const float4*)&Wb[(size_t)(kn + 16 + w0r) * RDH + j0 + w0c];
    }
#pragma unroll
    for (int k4 = 0; k4 < 8; ++k4) {
      const float4 a0 = *(const float4*)&a_s[(tb * 2 + 0) * 36 + k4 * 4];
      const float4 a1 = *(const float4*)&a_s[(tb * 2 + 1) * 36 + k4 * 4];
#pragma unroll
      for (int q = 0; q < 4; ++q) {
        const float4 w = *(const float4*)&w_s[(k4 * 4 + q) * 68 + tv * 4];
        const float a0q = (&a0.x)[q], a1q = (&a1.x)[q];
        acc[0][0] = fmaf(a0q, w.x, acc[0][0]);
        acc[0][1] = fmaf(a0q, w.y, acc[0][1]);
        acc[0][2] = fmaf(a0q, w.z, acc[0][2]);
        acc[0][3] = fmaf(a0q, w.w, acc[0][3]);
        acc[1][0] = fmaf(a1q, w.x, acc[1][0]);
        acc[1][1] = fmaf(a1q, w.y, acc[1][1]);
        acc[1][2] = fmaf(a1q, w.z, acc[1][2]);
        acc[1][3] = fmaf(a1q, w.w, acc[1][3]);
      }
    }
  }
#pragma unroll
  for (int i = 0; i < 2; ++i)
#pragma unroll
    for (int j = 0; j < 4; ++j)
      h[(size_t)(b0 + tb * 2 + i) * RDH + j0 + tv * 4 + j] = acc[i][j];
}

// ---------------------------------------------------------------------------
// GRU cell: x = relu(emb[topi]); gi = x@w_ih.T+b_ih; gh = h@w_hh.T+b_hh
// r = sig(i_r+h_r), z = sig(i_z+h_z), n = tanh(i_n + r*h_n)
// h_new = (1-z)*n + z*h
// r,z need only the SUM of the two dots -> 4 accumulators per (b,j).
// grid (RDH/32, RB/32), 256 threads, tile 32b x 32j.
// ---------------------------------------------------------------------------
__global__ __launch_bounds__(256) void k_gru(const float* __restrict__ h_in,
                                             float* __restrict__ h_out,
                                             const int* __restrict__ topi,
                                             const float* __restrict__ emb,
                                             const float* __restrict__ w_ih,
                                             const float* __restrict__ w_hh,
                                             const float* __restrict__ b_ih,
                                             const float* __restrict__ b_hh,
                                             int step) {
  __shared__ float a_s[32 * 36];
  __shared__ float w_sr[32 * 34];
  __shared__ float w_sz[32 * 34];
  __shared__ float w_sn[32 * 34];
  const int t = threadIdx.x;
  const int j0 = blockIdx.x * 32;
  const int b0 = blockIdx.y * 32;
  const int tv = t & 15, tb = t >> 4;
  const int arow = t >> 3, ac = (t & 7) * 4;
  const int wjj = t >> 3, wc = (t & 7) * 4;
  float ar[2][2] = {}, az[2][2] = {}, ain[2][2] = {}, ahn[2][2] = {};
  float4 pa, pwr, pwz, pwn;

  const int tok = (step == 0) ? RBOS : topi[b0 + arow];
  const float* xrow = emb + (size_t)tok * RDE;
  const float* wr_src = w_ih + (size_t)(0 * RDH + j0 + wjj) * RDE;
  const float* wz_src = w_ih + (size_t)(1 * RDH + j0 + wjj) * RDE;
  const float* wn_src = w_ih + (size_t)(2 * RDH + j0 + wjj) * RDE;
  const float* hrow = h_in + (size_t)(b0 + arow) * RDH;
  const float* hr_src = w_hh + (size_t)(0 * RDH + j0 + wjj) * RDH;
  const float* hz_src = w_hh + (size_t)(1 * RDH + j0 + wjj) * RDH;
  const float* hn_src = w_hh + (size_t)(2 * RDH + j0 + wjj) * RDH;

  // preload phase-1 chunk 0 (relu applied at load)
  {
    float4 v = *(const float4*)&xrow[ac];
    v.x = fmaxf(v.x, 0.f); v.y = fmaxf(v.y, 0.f);
    v.z = fmaxf(v.z, 0.f); v.w = fmaxf(v.w, 0.f);
    pa = v;
  }
  pwr = *(const float4*)&wr_src[wc];
  pwz = *(const float4*)&wz_src[wc];
  pwn = *(const float4*)&wn_src[wc];

#define GRU_STAGE()                                                    \
  do {                                                                 \
    *(float4*)&a_s[arow * 36 + ac] = pa;                               \
    _Pragma("unroll") for (int q = 0; q < 4; ++q) {                    \
      w_sr[(wc + q) * 34 + wjj] = (&pwr.x)[q];                         \
      w_sz[(wc + q) * 34 + wjj] = (&pwz.x)[q];                         \
      w_sn[(wc + q) * 34 + wjj] = (&pwn.x)[q];                         \
    }                                                                  \
  } while (0)

#define GRU_MMA(AN)                                                    \
  _Pragma("unroll") for (int k4 = 0; k4 < 8; ++k4) {                   \
    const float4 a0 = *(const float4*)&a_s[(tb * 2 + 0) * 36 + k4 * 4];\
    const float4 a1 = *(const float4*)&a_s[(tb * 2 + 1) * 36 + k4 * 4];\
    _Pragma("unroll") for (int q = 0; q < 4; ++q) {                    \
      const int kk = k4 * 4 + q;                                       \
      const float2 wr = *(const float2*)&w_sr[kk * 34 + tv * 2];       \
      const float2 wz = *(const float2*)&w_sz[kk * 34 + tv * 2];       \
      const float2 wn = *(const float2*)&w_sn[kk * 34 + tv * 2];       \
      const float a0q = (&a0.x)[q], a1q = (&a1.x)[q];                  \
      ar[0][0] = fmaf(a0q, wr.x, ar[0][0]);                            \
      ar[0][1] = fmaf(a0q, wr.y, ar[0][1]);                            \
      ar[1][0] = fmaf(a1q, wr.x, ar[1][0]);                            \
      ar[1][1] = fmaf(a1q, wr.y, ar[1][1]);                            \
      az[0][0] = fmaf(a0q, wz.x, az[0][0]);                            \
      az[0][1] = fmaf(a0q, wz.y, az[0][1]);                            \
      az[1][0] = fmaf(a1q, wz.x, az[1][0]);                            \
      az[1][1] = fmaf(a1q, wz.y, az[1][1]);                            \
      AN[0][0] = fmaf(a0q, wn.x, AN[0][0]);                            \
      AN[0][1] = fmaf(a0q, wn.y, AN[0][1]);                            \
      AN[1][0] = fmaf(a1q, wn.x, AN[1][0]);                            \
      AN[1][1] = fmaf(a1q, wn.y, AN[1][1]);                            \
    }                                                                  \
  }

  // phase 1: x-part (K = RDE)
  for (int kc = 0; kc < RDE; kc += 32) {
    __syncthreads();
    GRU_STAGE();
    __syncthreads();
    if (kc + 32 < RDE) {
      const int kn = kc + 32;
      float4 v = *(const float4*)&xrow[kn + ac];
      v.x = fmaxf(v.x, 0.f); v.y = fmaxf(v.y, 0.f);
      v.z = fmaxf(v.z, 0.f); v.w = fmaxf(v.w, 0.f);
      pa = v;
      pwr = *(const float4*)&wr_src[kn + wc];
      pwz = *(const float4*)&wz_src[kn + wc];
      pwn = *(const float4*)&wn_src[kn + wc];
    } else {  // preload phase-2 chunk 0
      pa = *(const float4*)&hrow[ac];
      pwr = *(const float4*)&hr_src[wc];
      pwz = *(const float4*)&hz_src[wc];
      pwn = *(const float4*)&hn_src[wc];
    }
    GRU_MMA(ain);
  }
  // phase 2: h-part (K = RDH)
  for (int kc = 0; kc < RDH; kc += 32) {
    __syncthreads();
    GRU_STAGE();
    __syncthreads();
    if (kc + 32 < RDH) {
      const int kn = kc + 32;
      pa = *(const float4*)&hrow[kn + ac];
      pwr = *(const float4*)&hr_src[kn + wc];
      pwz = *(const float4*)&hz_src[kn + wc];
      pwn = *(const float4*)&hn_src[kn + wc];
    }
    GRU_MMA(ahn);
  }
#undef GRU_STAGE
#undef GRU_MMA

  // pointwise GRU + write h_new
#pragma unroll
  for (int i = 0; i < 2; ++i) {
    const int b = b0 + tb * 2 + i;
#pragma unroll
    for (int jj = 0; jj < 2; ++jj) {
      const int j = j0 + tv * 2 + jj;
      const float sr = ar[i][jj] + b_ih[j] + b_hh[j];
      const float r = 1.f / (1.f + expf(-sr));
      const float sz = az[i][jj] + b_ih[RDH + j] + b_hh[RDH + j];
      const float z = 1.f / (1.f + expf(-sz));
      const float n =
          tanhf(ain[i][jj] + b_ih[2 * RDH + j] + r * (ahn[i][jj] + b_hh[2 * RDH + j]));
      const float hp = h_in[(size_t)b * RDH + j];
      h_out[(size_t)b * RDH + j] = (1.f - z) * n + z * hp;
    }
  }
}

// ---------------------------------------------------------------------------
// logits = h_new @ W_out.T + b_out + gumbel[t]; per-(b, v-tile) partial argmax
// grid (RNVT, RB/128), 256 threads, tile 128b x 64v, K = RDH chunks of 32.
// ---------------------------------------------------------------------------
__global__ __launch_bounds__(256) void k_logits(const float* __restrict__ h,
                                                const float* __restrict__ Wout,
                                                const float* __restrict__ bout,
                                                const float* __restrict__ gum_t,
                                                float* __restrict__ pval,
                                                int* __restrict__ pidx) {
  __shared__ float a_s[128 * 36];
  __shared__ float w_s[32 * 68];
  const int t = threadIdx.x;
  const int v0 = blockIdx.x * RVT;
  const int b0 = blockIdx.y * 128;
  const int tv = t & 15, tb = t >> 4;
  float acc[8][4] = {};
  float4 pa[4], pw[2];

#define LOG_PRELOAD(KC)                                                    \
  do {                                                                     \
    _Pragma("unroll") for (int i = 0; i < 4; ++i) {                        \
      const int idx = t + i * 256;                                         \
      const int row = idx >> 3, c4 = (idx & 7) * 4;                        \
      pa[i] = *(const float4*)&h[(size_t)(b0 + row) * RDH + (KC) + c4];    \
    }                                                                      \
    _Pragma("unroll") for (int i = 0; i < 2; ++i) {                        \
      const int idx = t + i * 256;                                         \
      const int vr = idx >> 3, c4 = (idx & 7) * 4;                         \
      int srow = v0 + vr; if (srow >= RV) srow = RV - 1;                   \
      pw[i] = *(const float4*)&Wout[(size_t)srow * RDH + (KC) + c4];       \
    }                                                                      \
  } while (0)

  LOG_PRELOAD(0);
  for (int kc = 0; kc < RDH; kc += 32) {
    __syncthreads();
#pragma unroll
    for (int i = 0; i < 4; ++i) {
      const int idx = t + i * 256;
      const int row = idx >> 3, c4 = (idx & 7) * 4;
      *(float4*)&a_s[row * 36 + c4] = pa[i];
    }
#pragma unroll
    for (int i = 0; i < 2; ++i) {
      const int idx = t + i * 256;
      const int vr = idx >> 3, c4 = (idx & 7) * 4;
#pragma unroll
      for (int q = 0; q < 4; ++q) w_s[(c4 + q) * 68 + vr] = (&pw[i].x)[q];
    }
    __syncthreads();
    if (kc + 32 < RDH) LOG_PRELOAD(kc + 32);
#pragma unroll
    for (int k4 = 0; k4 < 8; ++k4) {
      float4 wk[4];
#pragma unroll
      for (int q = 0; q < 4; ++q)
        wk[q] = *(const float4*)&w_s[(k4 * 4 + q) * 68 + tv * 4];
#pragma unroll
      for (int i = 0; i < 8; ++i) {
        const float4 a = *(const float4*)&a_s[(tb * 8 + i) * 36 + k4 * 4];
#pragma unroll
        for (int q = 0; q < 4; ++q) {
          const float av = (&a.x)[q];
          acc[i][0] = fmaf(av, wk[q].x, acc[i][0]);
          acc[i][1] = fmaf(av, wk[q].y, acc[i][1]);
          acc[i][2] = fmaf(av, wk[q].z, acc[i][2]);
          acc[i][3] = fmaf(av, wk[q].w, acc[i][3]);
        }
      }
    }
  }
#undef LOG_PRELOAD

  // epilogue: + b_out + gumbel, tile-local argmax (first-index tie-break)
  const int vbase = v0 + tv * 4;
  float bo[4];
#pragma unroll
  for (int j = 0; j < 4; ++j) bo[j] = (vbase + j < RV) ? bout[vbase + j] : 0.f;
#pragma unroll
  for (int i = 0; i < 8; ++i) {
    const int b = b0 + tb * 8 + i;
    const float* grow = gum_t + (size_t)b * RV;
    float mval = -FLT_MAX;
    int midx = vbase;
#pragma unroll
    for (int j = 0; j < 4; ++j) {
      const int v = vbase + j;
      float val = -FLT_MAX;
      if (v < RV) val = acc[i][j] + bo[j] + grow[v];
      if (val > mval) { mval = val; midx = v; }
    }
#pragma unroll
    for (int off = 1; off < 16; off <<= 1) {
      const float ov = __shfl_xor(mval, off);
      const int oi = __shfl_xor(midx, off);
      if (ov > mval || (ov == mval && oi < midx)) { mval = ov; midx = oi; }
    }
    if (tv == 0) {
      pval[(size_t)b * RNVT + blockIdx.x] = mval;
      pidx[(size_t)b * RNVT + blockIdx.x] = midx;
    }
  }
}

// ---------------------------------------------------------------------------
// finalize argmax over the RNVT partials; write topi, topi_seq, one-hot 1.0
// grid (RB), 64 threads
// ---------------------------------------------------------------------------
__global__ void k_argmax(const float* __restrict__ pval,
                         const int* __restrict__ pidx,
                         int* __restrict__ topi, int* __restrict__ tseq,
                         float* __restrict__ out, int step) {
  const int b = blockIdx.x;
  const int t = threadIdx.x;
  float mval = -FLT_MAX;
  int midx = RV;
  for (int m = t; m < RNVT; m += 64) {
    const float v = pval[(size_t)b * RNVT + m];
    const int i = pidx[(size_t)b * RNVT + m];
    if (v > mval || (v == mval && i < midx)) { mval = v; midx = i; }
  }
#pragma unroll
  for (int off = 1; off < 64; off <<= 1) {
    const float ov = __shfl_xor(mval, off);
    const int oi = __shfl_xor(midx, off);
    if (ov > mval || (ov == mval && oi < midx)) { mval = ov; midx = oi; }
  }
  if (t == 0) {
    topi[b] = midx;
    tseq[step * RB + b] = midx;
    out[((size_t)b * RS + step) * RV + midx] = 1.0f;
  }
}

// ---------------------------------------------------------------------------
// msg_lens: last EOS index + 1, else S.  grid (1), 256 threads
// ---------------------------------------------------------------------------
__global__ void k_msglens(const int* __restrict__ tseq, float* __restrict__ out_ml) {
  const int b = threadIdx.x;
  int last = -1;
  for (int s = 0; s < RS; ++s)
    if (tseq[s * RB + b] == REOS) last = s;
  out_ml[b] = (last >= 0) ? (float)(last + 1) : (float)RS;
}

// ---------------------------------------------------------------------------
extern "C" void kernel_launch(void* const* d_in, const int* in_sizes, int n_in,
                              void* d_out, int out_size, void* d_ws, size_t ws_size,
                              hipStream_t stream) {
  (void)in_sizes; (void)n_in; (void)out_size; (void)ws_size;
  const float* image = (const float*)d_in[0];
  const float* Wb    = (const float*)d_in[1];
  const float* emb   = (const float*)d_in[2];
  const float* w_ih  = (const float*)d_in[3];
  const float* w_hh  = (const float*)d_in[4];
  const float* b_ih  = (const float*)d_in[5];
  const float* b_hh  = (const float*)d_in[6];
  const float* Wout  = (const float*)d_in[7];
  const float* bout  = (const float*)d_in[8];
  const float* gum   = (const float*)d_in[9];
  float* out = (float*)d_out;

  float* h0b = (float*)d_ws;                       // [RB*RDH]
  float* h1b = h0b + (size_t)RB * RDH;             // [RB*RDH]
  float* pval = h1b + (size_t)RB * RDH;            // [RB*RNVT]
  int* pidx = (int*)(pval + (size_t)RB * RNVT);    // [RB*RNVT]
  int* topi = pidx + (size_t)RB * RNVT;            // [RB]
  int* tseq = topi + RB;                           // [RS*RB]

  // zero the one-hot region (poisoned 0xAA before every launch)
  hipMemsetAsync(d_out, 0, (size_t)RB * RS * RV * sizeof(float), stream);

  k_h0<<<dim3(RDH / 64, RB / 32), 256, 0, stream>>>(image, Wb, h0b);

  float* hb[2] = {h0b, h1b};
  for (int step = 0; step < RS; ++step) {
    float* hin = hb[step & 1];
    float* hout = hb[(step + 1) & 1];
    k_gru<<<dim3(RDH / 32, RB / 32), 256, 0, stream>>>(hin, hout, topi, emb,
                                                       w_ih, w_hh, b_ih, b_hh, step);
    k_logits<<<dim3(RNVT, RB / 128), 256, 0, stream>>>(hout, Wout, bout,
                                                       gum + (size_t)step * RB * RV,
                                                       pval, pidx);
    k_argmax<<<dim3(RB), 64, 0, stream>>>(pval, pidx, topi, tseq, out, step);
  }
  k_msglens<<<1, 256, 0, stream>>>(tseq, out + (size_t)RB * RS * RV);
}